// Round 2
// baseline (136.478 us; speedup 1.0000x reference)
//
#include <hip/hip_runtime.h>

// Fused: out = cos(x @ W_in^T + theta) @ W_out^T
// x: [262144, 64] f32, W_in: [64,64] f32, theta: [64] f32, W_out: [64,64] f32
// out: [262144, 64] f32
//
// One wave per block (64 rows/wave), 4096 blocks. No __syncthreads: the q
// LDS tile is wave-private, ordering enforced by a wave-local lgkmcnt fence.
// matmul1 swapped (D1 = W_in · x^T) so theta-add and the q bf16 pack are
// reg-local; LDS bounce (XOR-swizzled) relayouts q into B-fragments for
// matmul2 = mfma(W_out, q^T) -> non-temporal float4 stores.

typedef __attribute__((ext_vector_type(8))) short bf16x8;   // 8 bf16 in 4 VGPRs
typedef __attribute__((ext_vector_type(4))) float f32x4;

#define INV2PI 0.15915493667125702f

static __device__ __forceinline__ unsigned short f2bf(float f) {
  // round-to-nearest-even f32 -> bf16 (inputs are finite)
  unsigned int u = __float_as_uint(f);
  u += 0x7FFFu + ((u >> 16) & 1u);
  return (unsigned short)(u >> 16);
}

static __device__ __forceinline__ unsigned int pk2(float a, float b) {
  return (unsigned int)f2bf(a) | ((unsigned int)f2bf(b) << 16);
}

static __device__ __forceinline__ bf16x8 cvt8(f32x4 a, f32x4 b) {
  bf16x8 r;
  r[0] = (short)f2bf(a[0]); r[1] = (short)f2bf(a[1]);
  r[2] = (short)f2bf(a[2]); r[3] = (short)f2bf(a[3]);
  r[4] = (short)f2bf(b[0]); r[5] = (short)f2bf(b[1]);
  r[6] = (short)f2bf(b[2]); r[7] = (short)f2bf(b[3]);
  return r;
}

__global__ __launch_bounds__(64, 4) void mhaq_fused(
    const float* __restrict__ x, const float* __restrict__ Win,
    const float* __restrict__ theta, const float* __restrict__ Wout,
    float* __restrict__ out)
{
  const int lane = threadIdx.x & 63;
  const int g    = lane >> 4;            // lane group 0..3
  const int c    = lane & 15;            // 0..15
  const long rowb = (long)blockIdx.x * 64;

  // wave-private 64x64 bf16 q tile (8 KB), XOR-swizzled rows
  __shared__ char lds[64 * 128];

  // ---- x as B-fragments FIRST (long-latency HBM reads in flight early) ----
  // cols m = c + 16*mt, k = e = 32*ks + 8*g + j
  bf16x8 bx[4][2];
  #pragma unroll
  for (int mt = 0; mt < 4; ++mt) {
    #pragma unroll
    for (int ks = 0; ks < 2; ++ks) {
      const float* p = x + (rowb + c + 16*mt) * 64 + 32*ks + 8*g;
      bx[mt][ks] = cvt8(*(const f32x4*)p, *(const f32x4*)(p + 4));
    }
  }

  // ---- W_in as A-fragments: rows w = c + 16*wt, k = e = 32*ks + 8*g + j ----
  bf16x8 aWin[4][2];
  #pragma unroll
  for (int wt = 0; wt < 4; ++wt) {
    #pragma unroll
    for (int ks = 0; ks < 2; ++ks) {
      const float* p = Win + (c + 16*wt) * 64 + 32*ks + 8*g;
      aWin[wt][ks] = cvt8(*(const f32x4*)p, *(const f32x4*)(p + 4));
    }
  }

  // ---- theta, pre-scaled by 1/(2pi); element r maps to w = 16*wt + 4*g + r ----
  f32x4 th[4];
  #pragma unroll
  for (int wt = 0; wt < 4; ++wt) {
    f32x4 t = *(const f32x4*)(theta + 16*wt + 4*g);
    th[wt] = t * INV2PI;
  }

  // ---- matmul1: D1[w][m] = sum_e W_in[w][e] * x[m][e] ----
  // D layout: col m = c (+16*mt tile), row w = 4*g + r (+16*wt tile)
  f32x4 acc1[4][4];
  #pragma unroll
  for (int wt = 0; wt < 4; ++wt) {
    #pragma unroll
    for (int mt = 0; mt < 4; ++mt) {
      f32x4 a = {0.f, 0.f, 0.f, 0.f};
      a = __builtin_amdgcn_mfma_f32_16x16x32_bf16(aWin[wt][0], bx[mt][0], a, 0, 0, 0);
      a = __builtin_amdgcn_mfma_f32_16x16x32_bf16(aWin[wt][1], bx[mt][1], a, 0, 0, 0);
      acc1[wt][mt] = a;
    }
  }

  // ---- epilogue1: q = cos(token + theta), pack 4 consecutive w -> ds_write_b64 ----
  #pragma unroll
  for (int wt = 0; wt < 4; ++wt) {
    #pragma unroll
    for (int mt = 0; mt < 4; ++mt) {
      float q[4];
      #pragma unroll
      for (int r = 0; r < 4; ++r) {
        float rev = acc1[wt][mt][r] * INV2PI + th[wt][r];
        rev -= floorf(rev);                      // range-reduce to [0,1)
        q[r] = __builtin_amdgcn_cosf(rev);       // v_cos_f32: cos(2*pi*rev)
      }
      const int m = c + 16*mt;
      int off = m * 128 + (16*wt + 4*g) * 2;     // q[m][w] row-major, bf16
      off ^= (m & 7) << 4;                       // bank-conflict swizzle
      *(uint2*)(lds + off) = make_uint2(pk2(q[0], q[1]), pk2(q[2], q[3]));
    }
  }

  // wave-local LDS write->read ordering (tile is private to this wave; no
  // cross-wave barrier needed). "memory" clobber orders the ds ops.
  asm volatile("s_waitcnt lgkmcnt(0)" ::: "memory");

  // ---- W_out as A-fragments: rows o = c + 16*ot, k = w = 32*ks + 8*g + j ----
  bf16x8 aWout[4][2];
  #pragma unroll
  for (int ot = 0; ot < 4; ++ot) {
    #pragma unroll
    for (int ks = 0; ks < 2; ++ks) {
      const float* p = Wout + (c + 16*ot) * 64 + 32*ks + 8*g;
      aWout[ot][ks] = cvt8(*(const f32x4*)p, *(const f32x4*)(p + 4));
    }
  }

  // ---- q back as B-fragments: col m = c + 16*mt, k = w = 32*ks + 8*g + j ----
  bf16x8 qf[4][2];
  #pragma unroll
  for (int mt = 0; mt < 4; ++mt) {
    #pragma unroll
    for (int ks = 0; ks < 2; ++ks) {
      const int m = c + 16*mt;
      int off = m * 128 + (32*ks + 8*g) * 2;
      off ^= (m & 7) << 4;                       // same swizzle as write
      qf[mt][ks] = *(const bf16x8*)(lds + off);  // ds_read_b128
    }
  }

  // ---- matmul2: D2[o][m] = sum_w W_out[o][w] * q[m][w] = out[m][o] ----
  // D layout: col m = c (+16*mt), row o = 4*g + r (+16*ot) -> 4 consecutive o
  #pragma unroll
  for (int ot = 0; ot < 4; ++ot) {
    #pragma unroll
    for (int mt = 0; mt < 4; ++mt) {
      f32x4 a = {0.f, 0.f, 0.f, 0.f};
      a = __builtin_amdgcn_mfma_f32_16x16x32_bf16(aWout[ot][0], qf[mt][0], a, 0, 0, 0);
      a = __builtin_amdgcn_mfma_f32_16x16x32_bf16(aWout[ot][1], qf[mt][1], a, 0, 0, 0);
      // coalesced non-temporal float4 store: out[rowb + m][16*ot + 4*g .. +3]
      __builtin_nontemporal_store(
          a, (f32x4*)(out + (rowb + c + 16*mt) * 64 + 16*ot + 4*g));
    }
  }
}

extern "C" void kernel_launch(void* const* d_in, const int* in_sizes, int n_in,
                              void* d_out, int out_size, void* d_ws, size_t ws_size,
                              hipStream_t stream) {
  const float* x     = (const float*)d_in[0];
  const float* Win   = (const float*)d_in[1];
  const float* theta = (const float*)d_in[2];
  const float* Wout  = (const float*)d_in[3];
  float* out = (float*)d_out;

  // 262144 rows / 64 rows-per-wave = 4096 single-wave blocks
  dim3 grid(4096), block(64);
  hipLaunchKernelGGL(mhaq_fused, grid, block, 0, stream, x, Win, theta, Wout, out);
}

// Round 3
// 129.780 us; speedup vs baseline: 1.0516x; 1.0516x over previous
//
#include <hip/hip_runtime.h>

// Fused: out = cos(x @ W_in^T + theta) @ W_out^T
// x: [262144, 64] f32, W_in: [64,64] f32, theta: [64] f32, W_out: [64,64] f32
// out: [262144, 64] f32
//
// 1024 blocks x 128 threads (2 independent waves, no barrier). Each wave
// processes TWO 64-row tiles, software-pipelined: tile n+1's 16 dwordx4
// loads are issued right after tile n's cvt, so HBM reads fly under
// matmul1/cos/LDS/matmul2. All 16 raw loads land in VGPRs before any cvt
// (full memory-level parallelism). Cached (not nt) float4 stores: L2
// merges the 4x64B segments per row into full lines.

typedef __attribute__((ext_vector_type(8))) short bf16x8;   // 8 bf16 in 4 VGPRs
typedef __attribute__((ext_vector_type(4))) float f32x4;

#define INV2PI 0.15915493667125702f

static __device__ __forceinline__ unsigned short f2bf(float f) {
  // round-to-nearest-even f32 -> bf16 (inputs are finite)
  unsigned int u = __float_as_uint(f);
  u += 0x7FFFu + ((u >> 16) & 1u);
  return (unsigned short)(u >> 16);
}

static __device__ __forceinline__ unsigned int pk2(float a, float b) {
  return (unsigned int)f2bf(a) | ((unsigned int)f2bf(b) << 16);
}

static __device__ __forceinline__ bf16x8 cvt8(f32x4 a, f32x4 b) {
  bf16x8 r;
  r[0] = (short)f2bf(a[0]); r[1] = (short)f2bf(a[1]);
  r[2] = (short)f2bf(a[2]); r[3] = (short)f2bf(a[3]);
  r[4] = (short)f2bf(b[0]); r[5] = (short)f2bf(b[1]);
  r[6] = (short)f2bf(b[2]); r[7] = (short)f2bf(b[3]);
  return r;
}

__global__ __launch_bounds__(128, 2) void mhaq_fused(
    const float* __restrict__ x, const float* __restrict__ Win,
    const float* __restrict__ theta, const float* __restrict__ Wout,
    float* __restrict__ out)
{
  const int lane = threadIdx.x & 63;
  const int wv   = threadIdx.x >> 6;     // wave 0..1
  const int g    = lane >> 4;            // lane group 0..3
  const int c    = lane & 15;            // 0..15

  // wave-private 64x64 bf16 q tile (8 KB), XOR-swizzled rows
  __shared__ char lds_all[2][64 * 128];
  char* lds = lds_all[wv];

  // each wave owns 2 consecutive 64-row tiles
  const long rowb0 = ((long)blockIdx.x * 2 + wv) * 128;

  // ---- prologue: issue ALL 16 raw x loads for tile 0 (no cvt in between) ----
  f32x4 raw[16];
  #pragma unroll
  for (int mt = 0; mt < 4; ++mt) {
    #pragma unroll
    for (int ks = 0; ks < 2; ++ks) {
      const float* p = x + (rowb0 + c + 16*mt) * 64 + 32*ks + 8*g;
      raw[(mt*2 + ks)*2 + 0] = *(const f32x4*)p;
      raw[(mt*2 + ks)*2 + 1] = *(const f32x4*)(p + 4);
    }
  }

  // ---- weights hoisted (one cvt per wave) ----
  // W_in as A-fragments: rows w = c + 16*wt, k = e = 32*ks + 8*g + j
  bf16x8 aWin[4][2];
  #pragma unroll
  for (int wt = 0; wt < 4; ++wt) {
    #pragma unroll
    for (int ks = 0; ks < 2; ++ks) {
      const float* p = Win + (c + 16*wt) * 64 + 32*ks + 8*g;
      aWin[wt][ks] = cvt8(*(const f32x4*)p, *(const f32x4*)(p + 4));
    }
  }
  // W_out as A-fragments: rows o = c + 16*ot, k = w = 32*ks + 8*g + j
  bf16x8 aWout[4][2];
  #pragma unroll
  for (int ot = 0; ot < 4; ++ot) {
    #pragma unroll
    for (int ks = 0; ks < 2; ++ks) {
      const float* p = Wout + (c + 16*ot) * 64 + 32*ks + 8*g;
      aWout[ot][ks] = cvt8(*(const f32x4*)p, *(const f32x4*)(p + 4));
    }
  }
  // theta, pre-scaled by 1/(2pi); element r maps to w = 16*wt + 4*g + r
  f32x4 th[4];
  #pragma unroll
  for (int wt = 0; wt < 4; ++wt) {
    f32x4 t = *(const f32x4*)(theta + 16*wt + 4*g);
    th[wt] = t * INV2PI;
  }

  #pragma unroll
  for (int t = 0; t < 2; ++t) {
    const long rowb = rowb0 + (long)t * 64;

    // ---- cvt raw -> B-fragments (waits on this tile's loads) ----
    bf16x8 bx[4][2];
    #pragma unroll
    for (int mt = 0; mt < 4; ++mt) {
      #pragma unroll
      for (int ks = 0; ks < 2; ++ks) {
        bx[mt][ks] = cvt8(raw[(mt*2 + ks)*2], raw[(mt*2 + ks)*2 + 1]);
      }
    }

    // ---- issue next tile's 16 loads NOW (fly under the compute below) ----
    if (t == 0) {
      #pragma unroll
      for (int mt = 0; mt < 4; ++mt) {
        #pragma unroll
        for (int ks = 0; ks < 2; ++ks) {
          const float* p = x + (rowb0 + 64 + c + 16*mt) * 64 + 32*ks + 8*g;
          raw[(mt*2 + ks)*2 + 0] = *(const f32x4*)p;
          raw[(mt*2 + ks)*2 + 1] = *(const f32x4*)(p + 4);
        }
      }
    }

    // ---- matmul1 (wt at a time, small acc live range) + cos + pack -> LDS ----
    // D layout: col m = c (+16*mt tile), row w = 4*g + r (+16*wt tile)
    #pragma unroll
    for (int wt = 0; wt < 4; ++wt) {
      f32x4 acc[4];
      #pragma unroll
      for (int mt = 0; mt < 4; ++mt) {
        f32x4 a = {0.f, 0.f, 0.f, 0.f};
        a = __builtin_amdgcn_mfma_f32_16x16x32_bf16(aWin[wt][0], bx[mt][0], a, 0, 0, 0);
        a = __builtin_amdgcn_mfma_f32_16x16x32_bf16(aWin[wt][1], bx[mt][1], a, 0, 0, 0);
        acc[mt] = a;
      }
      #pragma unroll
      for (int mt = 0; mt < 4; ++mt) {
        float q[4];
        #pragma unroll
        for (int r = 0; r < 4; ++r) {
          float rev = acc[mt][r] * INV2PI + th[wt][r];
          rev -= floorf(rev);                      // range-reduce to [0,1)
          q[r] = __builtin_amdgcn_cosf(rev);       // v_cos_f32: cos(2*pi*rev)
        }
        const int m = c + 16*mt;
        int off = m * 128 + (16*wt + 4*g) * 2;     // q[m][w] row-major, bf16
        off ^= (m & 7) << 4;                       // bank-conflict swizzle
        *(uint2*)(lds + off) = make_uint2(pk2(q[0], q[1]), pk2(q[2], q[3]));
      }
    }

    // wave-local LDS write->read ordering (tile is private to this wave)
    asm volatile("s_waitcnt lgkmcnt(0)" ::: "memory");

    // ---- q back as B-fragments: col m = c + 16*mt, k = w = 32*ks + 8*g + j ----
    bf16x8 qf[4][2];
    #pragma unroll
    for (int mt = 0; mt < 4; ++mt) {
      #pragma unroll
      for (int ks = 0; ks < 2; ++ks) {
        const int m = c + 16*mt;
        int off = m * 128 + (32*ks + 8*g) * 2;
        off ^= (m & 7) << 4;                       // same swizzle as write
        qf[mt][ks] = *(const bf16x8*)(lds + off);  // ds_read_b128
      }
    }

    // ---- matmul2 (ot at a time) + cached coalesced float4 stores ----
    // D2[o][m] = out[m][o]; col m = c (+16*mt), row o = 4*g + r (+16*ot)
    #pragma unroll
    for (int ot = 0; ot < 4; ++ot) {
      f32x4 acc[4];
      #pragma unroll
      for (int mt = 0; mt < 4; ++mt) {
        f32x4 a = {0.f, 0.f, 0.f, 0.f};
        a = __builtin_amdgcn_mfma_f32_16x16x32_bf16(aWout[ot][0], qf[mt][0], a, 0, 0, 0);
        a = __builtin_amdgcn_mfma_f32_16x16x32_bf16(aWout[ot][1], qf[mt][1], a, 0, 0, 0);
        acc[mt] = a;
      }
      #pragma unroll
      for (int mt = 0; mt < 4; ++mt) {
        *(f32x4*)(out + (rowb + c + 16*mt) * 64 + 16*ot + 4*g) = acc[mt];
      }
    }
  }
}

extern "C" void kernel_launch(void* const* d_in, const int* in_sizes, int n_in,
                              void* d_out, int out_size, void* d_ws, size_t ws_size,
                              hipStream_t stream) {
  const float* x     = (const float*)d_in[0];
  const float* Win   = (const float*)d_in[1];
  const float* theta = (const float*)d_in[2];
  const float* Wout  = (const float*)d_in[3];
  float* out = (float*)d_out;

  // 262144 rows / (2 waves * 2 tiles * 64 rows) = 1024 blocks
  dim3 grid(1024), block(128);
  hipLaunchKernelGGL(mhaq_fused, grid, block, 0, stream, x, Win, theta, Wout, out);
}

// Round 4
// 125.252 us; speedup vs baseline: 1.0896x; 1.0362x over previous
//
#include <hip/hip_runtime.h>
#include <hip/hip_bf16.h>

// Fused: out = cos(x @ W_in^T + theta) @ W_out^T
// x: [262144, 64] f32, W_in: [64,64] f32, theta: [64] f32, W_out: [64,64] f32
// out: [262144, 64] f32
//
// 4096 blocks x 64 threads (1 wave each; 16 waves/CU grid-side), one 64-row
// tile per wave. All 16 raw dwordx4 x-loads issue before any conversion
// (full MLP); bf16 conversion uses the HW v_cvt_pk_bf16_f32 path via
// __float22bfloat162_rn instead of integer emulation (~3x fewer VALU ops).
// LDS bounce (XOR-swizzled, wave-private, lgkmcnt fence - no barrier)
// relayouts q for matmul2 = mfma(W_out, q^T) -> cached coalesced f32x4 stores.

typedef __attribute__((ext_vector_type(8))) short bf16x8;   // 8 bf16 in 4 VGPRs
typedef __attribute__((ext_vector_type(4))) float f32x4;

#define INV2PI 0.15915493667125702f

static __device__ __forceinline__ unsigned int pk2(float a, float b) {
  // 2 x f32 -> packed bf16x2 via HW cvt_pk (RNE)
  __hip_bfloat162 h = __float22bfloat162_rn(make_float2(a, b));
  union { __hip_bfloat162 h; unsigned int u; } u;
  u.h = h;
  return u.u;
}

static __device__ __forceinline__ bf16x8 cvt8(f32x4 a, f32x4 b) {
  union { bf16x8 v; __hip_bfloat162 h[4]; } u;
  u.h[0] = __float22bfloat162_rn(make_float2(a[0], a[1]));
  u.h[1] = __float22bfloat162_rn(make_float2(a[2], a[3]));
  u.h[2] = __float22bfloat162_rn(make_float2(b[0], b[1]));
  u.h[3] = __float22bfloat162_rn(make_float2(b[2], b[3]));
  return u.v;
}

__global__ __launch_bounds__(64, 4) void mhaq_fused(
    const float* __restrict__ x, const float* __restrict__ Win,
    const float* __restrict__ theta, const float* __restrict__ Wout,
    float* __restrict__ out)
{
  const int lane = threadIdx.x & 63;
  const int g    = lane >> 4;            // lane group 0..3
  const int c    = lane & 15;            // 0..15
  const long rowb = (long)blockIdx.x * 64;

  // wave-private 64x64 bf16 q tile (8 KB), XOR-swizzled rows
  __shared__ char lds[64 * 128];

  // ---- issue ALL 16 raw x dwordx4 loads first (no cvt in between) ----
  // fragment (mt,ks): cols m = c + 16*mt, k = e = 32*ks + 8*g + j
  f32x4 raw[16];
  #pragma unroll
  for (int mt = 0; mt < 4; ++mt) {
    #pragma unroll
    for (int ks = 0; ks < 2; ++ks) {
      const float* p = x + (rowb + c + 16*mt) * 64 + 32*ks + 8*g;
      raw[(mt*2 + ks)*2 + 0] = *(const f32x4*)p;
      raw[(mt*2 + ks)*2 + 1] = *(const f32x4*)(p + 4);
    }
  }

  // ---- weights (L2/L3-hot, broadcast across waves) ----
  // W_in as A-fragments: rows w = c + 16*wt, k = e = 32*ks + 8*g + j
  bf16x8 aWin[4][2];
  #pragma unroll
  for (int wt = 0; wt < 4; ++wt) {
    #pragma unroll
    for (int ks = 0; ks < 2; ++ks) {
      const float* p = Win + (c + 16*wt) * 64 + 32*ks + 8*g;
      aWin[wt][ks] = cvt8(*(const f32x4*)p, *(const f32x4*)(p + 4));
    }
  }
  // W_out as A-fragments: rows o = c + 16*ot, k = w = 32*ks + 8*g + j
  bf16x8 aWout[4][2];
  #pragma unroll
  for (int ot = 0; ot < 4; ++ot) {
    #pragma unroll
    for (int ks = 0; ks < 2; ++ks) {
      const float* p = Wout + (c + 16*ot) * 64 + 32*ks + 8*g;
      aWout[ot][ks] = cvt8(*(const f32x4*)p, *(const f32x4*)(p + 4));
    }
  }
  // theta, pre-scaled by 1/(2pi); element r maps to w = 16*wt + 4*g + r
  f32x4 th[4];
  #pragma unroll
  for (int wt = 0; wt < 4; ++wt) {
    f32x4 t = *(const f32x4*)(theta + 16*wt + 4*g);
    th[wt] = t * INV2PI;
  }

  // ---- cvt raw -> B-fragments (HW cvt_pk; waits on x loads here) ----
  bf16x8 bx[4][2];
  #pragma unroll
  for (int mt = 0; mt < 4; ++mt) {
    #pragma unroll
    for (int ks = 0; ks < 2; ++ks) {
      bx[mt][ks] = cvt8(raw[(mt*2 + ks)*2], raw[(mt*2 + ks)*2 + 1]);
    }
  }

  // ---- matmul1 (wt at a time) + cos + pack -> LDS ----
  // D layout: col m = c (+16*mt tile), row w = 4*g + r (+16*wt tile)
  #pragma unroll
  for (int wt = 0; wt < 4; ++wt) {
    f32x4 acc[4];
    #pragma unroll
    for (int mt = 0; mt < 4; ++mt) {
      f32x4 a = {0.f, 0.f, 0.f, 0.f};
      a = __builtin_amdgcn_mfma_f32_16x16x32_bf16(aWin[wt][0], bx[mt][0], a, 0, 0, 0);
      a = __builtin_amdgcn_mfma_f32_16x16x32_bf16(aWin[wt][1], bx[mt][1], a, 0, 0, 0);
      acc[mt] = a;
    }
    #pragma unroll
    for (int mt = 0; mt < 4; ++mt) {
      float q[4];
      #pragma unroll
      for (int r = 0; r < 4; ++r) {
        float rev = acc[mt][r] * INV2PI + th[wt][r];
        rev -= floorf(rev);                      // range-reduce to [0,1)
        q[r] = __builtin_amdgcn_cosf(rev);       // v_cos_f32: cos(2*pi*rev)
      }
      const int m = c + 16*mt;
      int off = m * 128 + (16*wt + 4*g) * 2;     // q[m][w] row-major, bf16
      off ^= (m & 7) << 4;                       // bank-conflict swizzle
      *(uint2*)(lds + off) = make_uint2(pk2(q[0], q[1]), pk2(q[2], q[3]));
    }
  }

  // wave-local LDS write->read ordering (tile is private to this wave)
  asm volatile("s_waitcnt lgkmcnt(0)" ::: "memory");

  // ---- q back as B-fragments: col m = c + 16*mt, k = w = 32*ks + 8*g + j ----
  bf16x8 qf[4][2];
  #pragma unroll
  for (int mt = 0; mt < 4; ++mt) {
    #pragma unroll
    for (int ks = 0; ks < 2; ++ks) {
      const int m = c + 16*mt;
      int off = m * 128 + (32*ks + 8*g) * 2;
      off ^= (m & 7) << 4;                       // same swizzle as write
      qf[mt][ks] = *(const bf16x8*)(lds + off);  // ds_read_b128
    }
  }

  // ---- matmul2 (ot at a time) + cached coalesced float4 stores ----
  // D2[o][m] = out[m][o]; col m = c (+16*mt), row o = 4*g + r (+16*ot)
  #pragma unroll
  for (int ot = 0; ot < 4; ++ot) {
    f32x4 acc[4];
    #pragma unroll
    for (int mt = 0; mt < 4; ++mt) {
      f32x4 a = {0.f, 0.f, 0.f, 0.f};
      a = __builtin_amdgcn_mfma_f32_16x16x32_bf16(aWout[ot][0], qf[mt][0], a, 0, 0, 0);
      a = __builtin_amdgcn_mfma_f32_16x16x32_bf16(aWout[ot][1], qf[mt][1], a, 0, 0, 0);
      acc[mt] = a;
    }
    #pragma unroll
    for (int mt = 0; mt < 4; ++mt) {
      *(f32x4*)(out + (rowb + c + 16*mt) * 64 + 16*ot + 4*g) = acc[mt];
    }
  }
}

extern "C" void kernel_launch(void* const* d_in, const int* in_sizes, int n_in,
                              void* d_out, int out_size, void* d_ws, size_t ws_size,
                              hipStream_t stream) {
  const float* x     = (const float*)d_in[0];
  const float* Win   = (const float*)d_in[1];
  const float* theta = (const float*)d_in[2];
  const float* Wout  = (const float*)d_in[3];
  float* out = (float*)d_out;

  // 262144 rows / 64 rows-per-wave = 4096 single-wave blocks
  dim3 grid(4096), block(64);
  hipLaunchKernelGGL(mhaq_fused, grid, block, 0, stream, x, Win, theta, Wout, out);
}